// Round 2
// baseline (903.457 us; speedup 1.0000x reference)
//
#include <hip/hip_runtime.h>

// CrossAttentionLayer: QKV proj -> scores(out#2) -> softmax (no-max, exp-sum) -> PV -> O proj -> +resid -> LN(out#1)
// All heavy GEMMs in bf16 MFMA 16x16x32, fp32 accumulate. Threshold 9.9e-2 absmax -> bf16 safe.
// R1 fix: staging loops covered only half the K-columns (r=idx>>2,c=idx&3 on a 64-wide tile)
//         -> uninitialized LDS -> NaN. Now r=idx>>3, c=idx&7 with full chunk counts.

typedef __bf16 bf16x8 __attribute__((ext_vector_type(8)));
typedef float f32x4 __attribute__((ext_vector_type(4)));

constexpr int cH = 1024, cNH = 16, cHD = 64, cB = 2, cLQ = 1024, cLKV = 4096;

__device__ __forceinline__ unsigned short f2b(float f) {
    union { float f; unsigned u; } v; v.f = f;
    unsigned u = v.u;
    return (unsigned short)((u + 0x7fffu + ((u >> 16) & 1u)) >> 16);
}

__global__ void cvt_kernel(const float* __restrict__ src, unsigned short* __restrict__ dst, int n4) {
    int i = blockIdx.x * blockDim.x + threadIdx.x;
    int stride = gridDim.x * blockDim.x;
    for (; i < n4; i += stride) {
        float4 f = ((const float4*)src)[i];
        ushort4 o;
        o.x = f2b(f.x); o.y = f2b(f.y); o.z = f2b(f.z); o.w = f2b(f.w);
        ((ushort4*)dst)[i] = o;
    }
}

// C[M,N] = A[M,K] @ W[N,K]^T + bias  (K=N=1024). EPI=0: bf16 out. EPI=1: fp32 out + residual.
template<int EPI>
__global__ __launch_bounds__(256) void gemm_bt(
    const unsigned short* __restrict__ A,
    const unsigned short* __restrict__ W,
    const float* __restrict__ bias,
    const float* __restrict__ resid,
    void* __restrict__ Cout)
{
    constexpr int K = 1024, N = 1024;
    __shared__ unsigned short Asm_[128 * 72];   // stride 72 (144B) breaks 128B bank aliasing, keeps 16B align
    __shared__ unsigned short Bsm_[128 * 72];
    const int m0 = blockIdx.x * 128, n0 = blockIdx.y * 128;
    const int t = threadIdx.x;
    const int wv = t >> 6, lane = t & 63, quad = lane >> 4, l16 = lane & 15;
    const int wm = (wv & 1) * 64, wn = (wv >> 1) * 64;

    f32x4 acc[4][4];
#pragma unroll
    for (int i = 0; i < 4; i++)
#pragma unroll
        for (int j = 0; j < 4; j++) acc[i][j] = f32x4{0.f, 0.f, 0.f, 0.f};

    for (int k0 = 0; k0 < K; k0 += 64) {
        __syncthreads();
        // 128 rows x 64 cols = 1024 bf16x8 chunks; 256 threads -> 4 each
#pragma unroll
        for (int i = 0; i < 4; i++) {
            int idx = t + i * 256;
            int r = idx >> 3, c = idx & 7;
            *(bf16x8*)(&Asm_[r * 72 + c * 8]) = *(const bf16x8*)(&A[(size_t)(m0 + r) * K + k0 + c * 8]);
            *(bf16x8*)(&Bsm_[r * 72 + c * 8]) = *(const bf16x8*)(&W[(size_t)(n0 + r) * K + k0 + c * 8]);
        }
        __syncthreads();
#pragma unroll
        for (int ks = 0; ks < 64; ks += 32) {
            bf16x8 af[4], bfr[4];
#pragma unroll
            for (int i = 0; i < 4; i++)
                af[i] = *(const bf16x8*)(&Asm_[(wm + 16 * i + l16) * 72 + ks + quad * 8]);
#pragma unroll
            for (int j = 0; j < 4; j++)
                bfr[j] = *(const bf16x8*)(&Bsm_[(wn + 16 * j + l16) * 72 + ks + quad * 8]);
#pragma unroll
            for (int i = 0; i < 4; i++)
#pragma unroll
                for (int j = 0; j < 4; j++)
                    acc[i][j] = __builtin_amdgcn_mfma_f32_16x16x32_bf16(af[i], bfr[j], acc[i][j], 0, 0, 0);
        }
    }
    // epilogue: C row = quad*4+reg, col = lane&15 (verified m89/m91 layout)
#pragma unroll
    for (int i = 0; i < 4; i++) {
#pragma unroll
        for (int j = 0; j < 4; j++) {
            int n = n0 + wn + 16 * j + l16;
            float bv = bias[n];
#pragma unroll
            for (int r = 0; r < 4; r++) {
                int m = m0 + wm + 16 * i + quad * 4 + r;
                float v = acc[i][j][r] + bv;
                if (EPI == 0) {
                    ((unsigned short*)Cout)[(size_t)m * N + n] = f2b(v);
                } else {
                    v += resid[(size_t)m * N + n];
                    ((float*)Cout)[(size_t)m * N + n] = v;
                }
            }
        }
    }
}

// One WG per (b, h, 64-row q tile). Writes scores to d_out, accumulates ctx = exp(S)@V / rowsum.
__global__ __launch_bounds__(256) void attn_kernel(
    const unsigned short* __restrict__ Qb,   // [B*LQ, H] bf16
    const unsigned short* __restrict__ Kb,   // [B*LKV, H] bf16
    const unsigned short* __restrict__ Vb,   // [B*LKV, H] bf16
    const int* __restrict__ mask,            // [B, LKV]
    float* __restrict__ scores,              // [B,NH,LQ,LKV] fp32
    unsigned short* __restrict__ ctx)        // [B*LQ, H] bf16 (merged heads)
{
    __shared__ unsigned short Qs[64 * 72];
    __shared__ unsigned short Ks[64 * 72];
    __shared__ unsigned short Vs[64 * 72];   // transposed: [d][kv]
    __shared__ unsigned short Ps[64 * 72];
    __shared__ int Ms[64];

    const int qt = blockIdx.x, h = blockIdx.y, b = blockIdx.z;
    const int t = threadIdx.x;
    const int wv = t >> 6, lane = t & 63, quad = lane >> 4, l16 = lane & 15;
    const int q0 = qt * 64;

    // Q tile: 64 rows x 64 cols = 512 chunks; 256 threads -> 2 each
#pragma unroll
    for (int i = 0; i < 2; i++) {
        int idx = t + i * 256;
        int r = idx >> 3, c = idx & 7;
        *(bf16x8*)(&Qs[r * 72 + c * 8]) =
            *(const bf16x8*)(&Qb[(size_t)(b * cLQ + q0 + r) * cH + h * cHD + c * 8]);
    }

    f32x4 cacc[4];
#pragma unroll
    for (int j = 0; j < 4; j++) cacc[j] = f32x4{0.f, 0.f, 0.f, 0.f};
    float rs[4] = {0.f, 0.f, 0.f, 0.f};

    float* srow = scores + (size_t)(b * cNH + h) * cLQ * cLKV;

    for (int kv0 = 0; kv0 < cLKV; kv0 += 64) {
        __syncthreads();
#pragma unroll
        for (int i = 0; i < 2; i++) {
            int idx = t + i * 256;
            int r = idx >> 3, c = idx & 7;
            *(bf16x8*)(&Ks[r * 72 + c * 8]) =
                *(const bf16x8*)(&Kb[(size_t)(b * cLKV + kv0 + r) * cH + h * cHD + c * 8]);
            union { bf16x8 v; unsigned short s[8]; } u;
            u.v = *(const bf16x8*)(&Vb[(size_t)(b * cLKV + kv0 + r) * cH + h * cHD + c * 8]);
#pragma unroll
            for (int j = 0; j < 8; j++)
                Vs[(c * 8 + j) * 72 + r] = u.s[j];
        }
        if (t < 64) Ms[t] = mask[b * cLKV + kv0 + t];
        __syncthreads();

        // S = Q K^T for this wave's 16 q-rows x 64 kv-cols
        f32x4 sacc[4];
#pragma unroll
        for (int j = 0; j < 4; j++) sacc[j] = f32x4{0.f, 0.f, 0.f, 0.f};
#pragma unroll
        for (int ks = 0; ks < 64; ks += 32) {
            bf16x8 aq = *(const bf16x8*)(&Qs[(wv * 16 + l16) * 72 + ks + quad * 8]);
#pragma unroll
            for (int nt = 0; nt < 4; nt++) {
                bf16x8 bk = *(const bf16x8*)(&Ks[(nt * 16 + l16) * 72 + ks + quad * 8]);
                sacc[nt] = __builtin_amdgcn_mfma_f32_16x16x32_bf16(aq, bk, sacc[nt], 0, 0, 0);
            }
        }

        // scale, mask, store scores, exp, row-sum partials, P -> LDS (A-layout consumable)
#pragma unroll
        for (int nt = 0; nt < 4; nt++) {
            int col = nt * 16 + l16;
            bool live = (Ms[col] != 0);
#pragma unroll
            for (int r = 0; r < 4; r++) {
                int qrow = wv * 16 + quad * 4 + r;
                float s = sacc[nt][r] * 0.125f;
                srow[(size_t)(q0 + qrow) * cLKV + kv0 + col] = live ? s : -__builtin_inff();
                float p = live ? __expf(s) : 0.f;
                rs[r] += p;
                Ps[qrow * 72 + col] = f2b(p);
            }
        }
        __syncthreads();

        // ctx += P @ V
#pragma unroll
        for (int ks = 0; ks < 64; ks += 32) {
            bf16x8 ap = *(const bf16x8*)(&Ps[(wv * 16 + l16) * 72 + ks + quad * 8]);
#pragma unroll
            for (int dt = 0; dt < 4; dt++) {
                bf16x8 bv = *(const bf16x8*)(&Vs[(dt * 16 + l16) * 72 + ks + quad * 8]);
                cacc[dt] = __builtin_amdgcn_mfma_f32_16x16x32_bf16(ap, bv, cacc[dt], 0, 0, 0);
            }
        }
    }

    // finalize row sums: reduce across the 16 lanes of each quad (cols); rows = quad*4+r
#pragma unroll
    for (int r = 0; r < 4; r++) {
        float v = rs[r];
        v += __shfl_xor(v, 1);
        v += __shfl_xor(v, 2);
        v += __shfl_xor(v, 4);
        v += __shfl_xor(v, 8);
        rs[r] = v;
    }
#pragma unroll
    for (int dt = 0; dt < 4; dt++) {
#pragma unroll
        for (int r = 0; r < 4; r++) {
            int qrow = wv * 16 + quad * 4 + r;
            ctx[(size_t)(b * cLQ + q0 + qrow) * cH + h * cHD + dt * 16 + l16] = f2b(cacc[dt][r] / rs[r]);
        }
    }
}

__global__ __launch_bounds__(256) void ln_kernel(
    const float* __restrict__ y,
    const float* __restrict__ lw,
    const float* __restrict__ lb,
    float* __restrict__ out)
{
    __shared__ float red[8];
    const int row = blockIdx.x, t = threadIdx.x;
    const float* yr = y + (size_t)row * cH;
    float4 v = ((const float4*)yr)[t];
    float s1 = v.x + v.y + v.z + v.w;
    float s2 = v.x * v.x + v.y * v.y + v.z * v.z + v.w * v.w;
#pragma unroll
    for (int o = 1; o < 64; o <<= 1) {
        s1 += __shfl_xor(s1, o);
        s2 += __shfl_xor(s2, o);
    }
    if ((t & 63) == 0) { red[t >> 6] = s1; red[4 + (t >> 6)] = s2; }
    __syncthreads();
    s1 = red[0] + red[1] + red[2] + red[3];
    s2 = red[4] + red[5] + red[6] + red[7];
    float mu = s1 * (1.f / 1024.f);
    float var = s2 * (1.f / 1024.f) - mu * mu;
    float inv = rsqrtf(fmaxf(var, 0.f) + 1e-12f);
    float4 w4 = ((const float4*)lw)[t];
    float4 b4 = ((const float4*)lb)[t];
    float4 o4;
    o4.x = (v.x - mu) * inv * w4.x + b4.x;
    o4.y = (v.y - mu) * inv * w4.y + b4.y;
    o4.z = (v.z - mu) * inv * w4.z + b4.z;
    o4.w = (v.w - mu) * inv * w4.w + b4.w;
    ((float4*)(out + (size_t)row * cH))[t] = o4;
}

extern "C" void kernel_launch(void* const* d_in, const int* in_sizes, int n_in,
                              void* d_out, int out_size, void* d_ws, size_t ws_size,
                              hipStream_t stream) {
    (void)in_sizes; (void)n_in; (void)out_size; (void)ws_size;
    const float* hidden = (const float*)d_in[0];
    const float* enc    = (const float*)d_in[1];
    const int*   mask   = (const int*)d_in[2];
    const float* q_w = (const float*)d_in[3];
    const float* q_b = (const float*)d_in[4];
    const float* k_w = (const float*)d_in[5];
    const float* k_b = (const float*)d_in[6];
    const float* v_w = (const float*)d_in[7];
    const float* v_b = (const float*)d_in[8];
    const float* o_w = (const float*)d_in[9];
    const float* o_b = (const float*)d_in[10];
    const float* lnw = (const float*)d_in[11];
    const float* lnb = (const float*)d_in[12];

    char* ws = (char*)d_ws;
    unsigned short* hid_b = (unsigned short*)(ws);                        // 4 MiB
    unsigned short* enc_b = (unsigned short*)(ws + ((size_t)4  << 20));   // 16 MiB
    unsigned short* qw_b  = (unsigned short*)(ws + ((size_t)20 << 20));   // 2 MiB
    unsigned short* kw_b  = (unsigned short*)(ws + ((size_t)22 << 20));
    unsigned short* vw_b  = (unsigned short*)(ws + ((size_t)24 << 20));
    unsigned short* ow_b  = (unsigned short*)(ws + ((size_t)26 << 20));
    unsigned short* Qb    = (unsigned short*)(ws + ((size_t)28 << 20));   // 4 MiB
    unsigned short* Kb    = (unsigned short*)(ws + ((size_t)32 << 20));   // 16 MiB
    unsigned short* Vb    = (unsigned short*)(ws + ((size_t)48 << 20));   // 16 MiB
    unsigned short* ctxb  = (unsigned short*)(ws + ((size_t)64 << 20));   // 4 MiB
    float*          yb    = (float*)(ws + ((size_t)68 << 20));            // 8 MiB

    float* out_ln = (float*)d_out;
    float* out_sc = (float*)d_out + (size_t)cB * cLQ * cH;

    // fp32 -> bf16 staging
    cvt_kernel<<<(cB * cLQ * cH / 4 + 255) / 256, 256, 0, stream>>>(hidden, hid_b, cB * cLQ * cH / 4);
    cvt_kernel<<<(cB * cLKV * cH / 4 + 255) / 256, 256, 0, stream>>>(enc, enc_b, cB * cLKV * cH / 4);
    cvt_kernel<<<(cH * cH / 4 + 255) / 256, 256, 0, stream>>>(q_w, qw_b, cH * cH / 4);
    cvt_kernel<<<(cH * cH / 4 + 255) / 256, 256, 0, stream>>>(k_w, kw_b, cH * cH / 4);
    cvt_kernel<<<(cH * cH / 4 + 255) / 256, 256, 0, stream>>>(v_w, vw_b, cH * cH / 4);
    cvt_kernel<<<(cH * cH / 4 + 255) / 256, 256, 0, stream>>>(o_w, ow_b, cH * cH / 4);

    // projections
    gemm_bt<0><<<dim3(cB * cLQ / 128, 8), 256, 0, stream>>>(hid_b, qw_b, q_b, nullptr, (void*)Qb);
    gemm_bt<0><<<dim3(cB * cLKV / 128, 8), 256, 0, stream>>>(enc_b, kw_b, k_b, nullptr, (void*)Kb);
    gemm_bt<0><<<dim3(cB * cLKV / 128, 8), 256, 0, stream>>>(enc_b, vw_b, v_b, nullptr, (void*)Vb);

    // fused scores + softmax + PV
    attn_kernel<<<dim3(cLQ / 64, cNH, cB), 256, 0, stream>>>(Qb, Kb, Vb, mask, out_sc, ctxb);

    // output projection + bias + residual, then LayerNorm
    gemm_bt<1><<<dim3(cB * cLQ / 128, 8), 256, 0, stream>>>(ctxb, ow_b, o_b, hidden, (void*)yb);
    ln_kernel<<<cB * cLQ, 256, 0, stream>>>(yb, lnw, lnb, out_ln);
}